// Round 5
// baseline (127.440 us; speedup 1.0000x reference)
//
#include <hip/hip_runtime.h>
#include <hip/hip_bf16.h>
#include <math.h>

#define MM 8192
#define CC 4096
#define DD 768
#define EPSF 1e-8f

#define BM 256
#define BN 256
#define BK 64
#define TPB 512
#define NKT (DD / BK)          // 12 K-tiles
#define NROWT (MM / BM)        // 32
#define NCOLT (CC / BN)        // 16

// ---- ws layout ----
#define XB_OFF 0
#define YB_OFF (MM * DD * 2)
#define FW_OFF (YB_OFF + CC * DD * 2)
#define S_T 0
#define T_T (MM)
#define S_L (2 * MM)
#define T_L (2 * MM + CC)
#define CA_T (2 * MM + 2 * CC)         // t_t / s_t per text row
#define POS  (CA_T + MM)
#define PART (POS + MM)                // MM * NCOLT * 2 floats (top-2 largest u)

typedef __attribute__((ext_vector_type(8))) short short8;
typedef __attribute__((ext_vector_type(4))) unsigned short u16x4;
typedef __attribute__((ext_vector_type(4))) float f32x4;

__device__ inline unsigned short f2bf(float f) {
    unsigned int u = __float_as_uint(f);
    u += 0x7FFF + ((u >> 16) & 1);   // RNE
    return (unsigned short)(u >> 16);
}

__device__ inline void gll16(const void* g, void* l) {
    __builtin_amdgcn_global_load_lds(
        (const __attribute__((address_space(1))) void*)(uintptr_t)g,
        (__attribute__((address_space(3))) void*)(unsigned)(uintptr_t)l,
        16, 0, 0);
}

#define BAR() do { __builtin_amdgcn_sched_barrier(0); __builtin_amdgcn_s_barrier(); __builtin_amdgcn_sched_barrier(0); } while (0)
#define VM4 asm volatile("s_waitcnt vmcnt(4)" ::: "memory")
#define VM0 asm volatile("s_waitcnt vmcnt(0)" ::: "memory")
#define NOPS ((void)0)

// inline-asm LDS read: keeps the compiler from inserting conservative vmcnt(0)
// before fragment reads of global_load_lds-written LDS.
#define DSR(dst, base, off) \
    asm volatile("ds_read_b128 %0, %1 offset:%c2" : "=v"(dst) : "v"(base), "n"(off))

#define MFMA_B(a, b, c) __builtin_amdgcn_mfma_f32_16x16x32_bf16((a), (b), (c), 0, 0, 0)

// ---------------- prep+convert: per-row s,t,ca + bf16 copies ----------------
__global__ void prep_conv_kernel(const float* __restrict__ X, const float* __restrict__ Y,
                                 const float* curv_log, const float* ta_log, const float* la_log,
                                 char* __restrict__ wsb) {
    unsigned short* Xb = (unsigned short*)(wsb + XB_OFF);
    unsigned short* Yb = (unsigned short*)(wsb + YB_OFF);
    float* fws = (float*)(wsb + FW_OFF);
    int wid = threadIdx.x >> 6, lane = threadIdx.x & 63;
    int row = blockIdx.x * 4 + wid;
    float curv = __expf(curv_log[0]);
    const float* src; unsigned short* dst; float alpha; int idx; int is_text;
    if (row < MM) {
        src = X + (size_t)row * DD; dst = Xb + (size_t)row * DD;
        alpha = __expf(ta_log[0]); idx = row; is_text = 1;
    } else {
        int r = row - MM;
        src = Y + (size_t)r * DD; dst = Yb + (size_t)r * DD;
        alpha = __expf(la_log[0]); idx = r; is_text = 0;
    }
    float n2 = 0.f;
    #pragma unroll
    for (int j = 0; j < 3; ++j) {
        float4 v = *(const float4*)(src + lane * 4 + 256 * j);
        n2 += v.x * v.x + v.y * v.y + v.z * v.z + v.w * v.w;
        u16x4 o; o[0] = f2bf(v.x); o[1] = f2bf(v.y); o[2] = f2bf(v.z); o[3] = f2bf(v.w);
        *(u16x4*)(dst + lane * 4 + 256 * j) = o;
    }
    #pragma unroll
    for (int m = 32; m; m >>= 1) n2 += __shfl_xor(n2, m);
    if (lane == 0) {
        float r = sqrtf(curv) * alpha * sqrtf(n2);
        float s = alpha * sinhf(r) / fmaxf(r, EPSF);
        float tt = sqrtf(1.0f / curv + s * s * n2);
        if (is_text) {
            fws[S_T + idx] = s; fws[T_T + idx] = tt; fws[CA_T + idx] = tt / s;
        } else {
            fws[S_L + idx] = s; fws[T_L + idx] = tt;
        }
    }
}

// ---------------- pos: exact fp32 positive distance ----------------
__global__ void pos_kernel(const float* __restrict__ X, const float* __restrict__ Y,
                           const int* __restrict__ tgt, const float* curv_log,
                           char* __restrict__ wsb) {
    float* fws = (float*)(wsb + FW_OFF);
    int wid = threadIdx.x >> 6, lane = threadIdx.x & 63;
    int row = blockIdx.x * 4 + wid;
    if (row >= MM) return;
    float curv = __expf(curv_log[0]);
    int t = tgt[row];
    const float* xr = X + (size_t)row * DD;
    const float* yr = Y + (size_t)t * DD;
    float dot = 0.f;
    #pragma unroll
    for (int k = 0; k < DD / 64; ++k) dot += xr[lane + 64 * k] * yr[lane + 64 * k];
    #pragma unroll
    for (int m = 32; m; m >>= 1) dot += __shfl_xor(dot, m);
    if (lane == 0) {
        float inner = fws[S_T + row] * fws[S_L + t] * dot - fws[T_T + row] * fws[T_L + t];
        float cd = fmaxf(-curv * inner, 1.0f + EPSF);
        float d = __logf(cd + sqrtf(cd * cd - 1.0f)) * rsqrtf(curv);
        fws[POS + row] = d;
    }
}

// ---------------- main: 256x256 8-phase (rolled, asm ds_read) + top-2 largest u ----------------
__global__ __launch_bounds__(TPB, 2) void main_kernel(
    const int* __restrict__ tgt, char* __restrict__ wsb)
{
    // region rg = (kt&1)*2 + khalf; region = [kg 0..3][row 0..255][8] = 8192 ushorts (16KB)
    __shared__ unsigned short Ald[4 * 8192];   // 64KB
    __shared__ unsigned short Bld[4 * 8192];   // 64KB
    __shared__ float red[256][4][2];           // 8KB

    const unsigned short* Xb = (const unsigned short*)(wsb + XB_OFF);
    const unsigned short* Yb = (const unsigned short*)(wsb + YB_OFF);
    float* fws = (float*)(wsb + FW_OFF);

    int tid = threadIdx.x;
    int lane = tid & 63, wid = tid >> 6;
    int wr = wid >> 2, wc = wid & 3;           // 2 row-groups x 4 col-groups
    int l15 = lane & 15, rgrp = lane >> 4;

    // XCD-bijective swizzle: 512 blocks, xcd = bid&7 owns 4 rowpanels x all 16 coltiles
    int bid = blockIdx.x;
    int pos = bid >> 3;
    int coltile = pos >> 2;                    // 0..15
    int rowpanel = (bid & 7) * 4 + (pos & 3);  // 0..31
    int rowbase = rowpanel * BM;
    int colbase = coltile * BN;

    // staging: thread t covers chunks t and t+512 of each 16KB region
    const unsigned short* xk = Xb + (size_t)(rowbase + (tid & 255)) * DD + ((tid >> 8) * 8);
    const unsigned short* yk = Yb + (size_t)(colbase + (tid & 255)) * DD + ((tid >> 8) * 8);
    unsigned short* adst = Ald + tid * 8;
    unsigned short* bdst = Bld + tid * 8;

    // stage (src k-elem offset OFF from xk/yk) into region RG
#define STG_A(OFF, RG) do { gll16(xk + (OFF), adst + (RG) * 8192); \
                            gll16(xk + (OFF) + 16, adst + (RG) * 8192 + 4096); } while (0)
#define STG_B(OFF, RG) do { gll16(yk + (OFF), bdst + (RG) * 8192); \
                            gll16(yk + (OFF) + 16, bdst + (RG) * 8192 + 4096); } while (0)

    // lane fragment LDS byte bases (truncation to LDS offset validated by gll16 round-trip)
    unsigned a_base = (unsigned)(uintptr_t)(&Ald[0]) + rgrp * 4096 + (wr * 128 + l15) * 16;
    unsigned b_base = (unsigned)(uintptr_t)(&Bld[0]) + rgrp * 4096 + (wc * 64 + l15) * 16;

    f32x4 acc[8][4];
    #pragma unroll
    for (int a = 0; a < 8; ++a)
        #pragma unroll
        for (int b = 0; b < 4; ++b)
            acc[a][b] = (f32x4){0.f, 0.f, 0.f, 0.f};

    short8 af[4], bf[4];

#define MF16(AO) do { \
    acc[(AO)+0][0] = MFMA_B(af[0], bf[0], acc[(AO)+0][0]); \
    acc[(AO)+0][1] = MFMA_B(af[0], bf[1], acc[(AO)+0][1]); \
    acc[(AO)+0][2] = MFMA_B(af[0], bf[2], acc[(AO)+0][2]); \
    acc[(AO)+0][3] = MFMA_B(af[0], bf[3], acc[(AO)+0][3]); \
    acc[(AO)+1][0] = MFMA_B(af[1], bf[0], acc[(AO)+1][0]); \
    acc[(AO)+1][1] = MFMA_B(af[1], bf[1], acc[(AO)+1][1]); \
    acc[(AO)+1][2] = MFMA_B(af[1], bf[2], acc[(AO)+1][2]); \
    acc[(AO)+1][3] = MFMA_B(af[1], bf[3], acc[(AO)+1][3]); \
    acc[(AO)+2][0] = MFMA_B(af[2], bf[0], acc[(AO)+2][0]); \
    acc[(AO)+2][1] = MFMA_B(af[2], bf[1], acc[(AO)+2][1]); \
    acc[(AO)+2][2] = MFMA_B(af[2], bf[2], acc[(AO)+2][2]); \
    acc[(AO)+2][3] = MFMA_B(af[2], bf[3], acc[(AO)+2][3]); \
    acc[(AO)+3][0] = MFMA_B(af[3], bf[0], acc[(AO)+3][0]); \
    acc[(AO)+3][1] = MFMA_B(af[3], bf[1], acc[(AO)+3][1]); \
    acc[(AO)+3][2] = MFMA_B(af[3], bf[2], acc[(AO)+3][2]); \
    acc[(AO)+3][3] = MFMA_B(af[3], bf[3], acc[(AO)+3][3]); \
} while (0)

    // one phase: [wait] -> asm ds_reads -> stage -> barrier -> lgkm(0) -> MFMA cluster -> barrier
#define PHASE(RG, MH, AO, PRE, STG) do { \
    PRE; \
    if ((MH) == 0) { \
        DSR(bf[0], b_base, (RG) * 16384 + 0); \
        DSR(bf[1], b_base, (RG) * 16384 + 256); \
        DSR(bf[2], b_base, (RG) * 16384 + 512); \
        DSR(bf[3], b_base, (RG) * 16384 + 768); \
    } \
    DSR(af[0], a_base, (RG) * 16384 + (MH) * 1024 + 0); \
    DSR(af[1], a_base, (RG) * 16384 + (MH) * 1024 + 256); \
    DSR(af[2], a_base, (RG) * 16384 + (MH) * 1024 + 512); \
    DSR(af[3], a_base, (RG) * 16384 + (MH) * 1024 + 768); \
    STG; \
    BAR(); \
    asm volatile("s_waitcnt lgkmcnt(0)" ::: "memory"); \
    __builtin_amdgcn_sched_barrier(0); \
    __builtin_amdgcn_s_setprio(1); \
    MF16(AO); \
    __builtin_amdgcn_s_setprio(0); \
    BAR(); \
} while (0)

    // 8 phases = 2 K-tiles (kt even: regions 0/1; kt+1: regions 2/3)
#define PAIRB(S0, S1, S2, S3, S4, S5, S6, S7, W0, W4) do { \
    PHASE(0, 0, 0, W0, S0); \
    PHASE(0, 1, 4, NOPS, S1); \
    PHASE(1, 0, 0, NOPS, S2); \
    PHASE(1, 1, 4, NOPS, S3); \
    PHASE(2, 0, 0, W4, S4); \
    PHASE(2, 1, 4, NOPS, S5); \
    PHASE(3, 0, 0, NOPS, S6); \
    PHASE(3, 1, 4, NOPS, S7); \
} while (0)

    // prologue: stage (0,0),(0,1),(1,0); drain first two half-tiles
    STG_A(0, 0);  STG_B(0, 0);
    STG_A(32, 1); STG_B(32, 1);
    STG_A(64, 2); STG_B(64, 2);
    VM4;
    BAR();

    // 5 full pairs: kt = 0,2,4,6,8 (stages reference kt+1..kt+3, all in bounds)
    #pragma unroll 1
    for (int kp = 0; kp < 5; ++kp) {
        PAIRB(STG_A(96, 3), STG_B(96, 3), STG_A(128, 0), STG_B(128, 0),
              STG_A(160, 1), STG_B(160, 1), STG_A(192, 2), STG_B(192, 2),
              VM4, VM4);
        xk += 128; yk += 128;
    }
    // tail pair: kt = 10,11 — only (11,1) remains to stage
    PAIRB(STG_A(96, 3), STG_B(96, 3), NOPS, NOPS, NOPS, NOPS, NOPS, NOPS,
          VM4, VM0);

    // ---- epilogue: per-row top-2 of u = sb*dot - ca*tb (argtop2 == top2 of inner; sa>0) ----
    int colb = colbase + wc * 64 + l15;
    float sbv[4], tbv[4];
    #pragma unroll
    for (int nf = 0; nf < 4; ++nf) { sbv[nf] = fws[S_L + colb + nf * 16]; tbv[nf] = fws[T_L + colb + nf * 16]; }

    float m1[32], m2[32];
    #pragma unroll
    for (int mf = 0; mf < 8; ++mf) {
        int rw = rowbase + wr * 128 + mf * 16 + rgrp * 4;
        #pragma unroll
        for (int j = 0; j < 4; ++j) {
            float ca = fws[CA_T + rw + j];
            int tgj = tgt[rw + j];
            float a = -3.4e38f, b = -3.4e38f;
            #pragma unroll
            for (int nf = 0; nf < 4; ++nf) {
                float u = sbv[nf] * acc[mf][nf][j] - ca * tbv[nf];
                if (colb + nf * 16 == tgj) u = -3.4e38f;
                float n1 = fmaxf(a, u);
                b = fmaxf(b, fminf(a, u));
                a = n1;
            }
            m1[mf * 4 + j] = a; m2[mf * 4 + j] = b;
        }
    }
    #pragma unroll
    for (int mask = 1; mask <= 8; mask <<= 1)
        #pragma unroll
        for (int i = 0; i < 32; ++i) {
            float o1 = __shfl_xor(m1[i], mask);
            float o2 = __shfl_xor(m2[i], mask);
            float n1 = fmaxf(m1[i], o1);
            m2[i] = fmaxf(fminf(m1[i], o1), fmaxf(m2[i], o2));
            m1[i] = n1;
        }
    if (l15 == 0) {
        #pragma unroll
        for (int mf = 0; mf < 8; ++mf)
            #pragma unroll
            for (int j = 0; j < 4; ++j) {
                int rl = wr * 128 + mf * 16 + rgrp * 4 + j;
                red[rl][wc][0] = m1[mf * 4 + j];
                red[rl][wc][1] = m2[mf * 4 + j];
            }
    }
    __syncthreads();
    if (tid < 256) {
        float p1 = -3.4e38f, p2 = -3.4e38f;
        #pragma unroll
        for (int g = 0; g < 4; ++g) {
            float a1 = red[tid][g][0], a2 = red[tid][g][1];
            float n1 = fmaxf(p1, a1);
            p2 = fmaxf(fminf(p1, a1), fmaxf(p2, a2));
            p1 = n1;
        }
        int row = rowbase + tid;
        fws[PART + ((size_t)row * NCOLT + coltile) * 2 + 0] = p1;
        fws[PART + ((size_t)row * NCOLT + coltile) * 2 + 1] = p2;
    }
}

// ---------------- final: merge partials, arccosh on winners, loss ----------------
__global__ void final_kernel(const char* __restrict__ wsb, const float* __restrict__ curv_log,
                             float* __restrict__ out) {
    const float* fws = (const float*)(wsb + FW_OFF);
    int row = blockIdx.x * 256 + threadIdx.x;
    if (row >= MM) return;
    float curv = __expf(curv_log[0]);
    float rsc = rsqrtf(curv);
    const float* p = fws + PART + (size_t)row * (NCOLT * 2);
    float p1 = -3.4e38f, p2 = -3.4e38f;
    #pragma unroll
    for (int s = 0; s < NCOLT; ++s) {
        float a1 = p[s * 2], a2 = p[s * 2 + 1];
        float n1 = fmaxf(p1, a1);
        p2 = fmaxf(fminf(p1, a1), fmaxf(p2, a2));
        p1 = n1;
    }
    float sa = fws[S_T + row];
    float i1 = sa * p1, i2 = sa * p2;          // back to Lorentz inner
    float cd1 = fmaxf(-curv * i1, 1.0f + EPSF);
    float d1 = __logf(cd1 + sqrtf(cd1 * cd1 - 1.0f)) * rsc;
    float cd2 = fmaxf(-curv * i2, 1.0f + EPSF);
    float d2 = __logf(cd2 + sqrtf(cd2 * cd2 - 1.0f)) * rsc;
    float dp = fws[POS + row];
    float denom = __expf(-dp) + __expf(-d1) + __expf(-d2);
    out[row] = __logf(denom) + dp;
}

extern "C" void kernel_launch(void* const* d_in, const int* in_sizes, int n_in,
                              void* d_out, int out_size, void* d_ws, size_t ws_size,
                              hipStream_t stream) {
    const float* X = (const float*)d_in[0];
    const float* Y = (const float*)d_in[1];
    const int* tgt = (const int*)d_in[2];
    const float* curv_log = (const float*)d_in[3];
    const float* ta_log = (const float*)d_in[4];
    const float* la_log = (const float*)d_in[5];
    char* wsb = (char*)d_ws;
    float* out = (float*)d_out;

    prep_conv_kernel<<<(MM + CC) / 4, 256, 0, stream>>>(X, Y, curv_log, ta_log, la_log, wsb);
    pos_kernel<<<MM / 4, 256, 0, stream>>>(X, Y, tgt, curv_log, wsb);
    main_kernel<<<NROWT * NCOLT, TPB, 0, stream>>>(tgt, wsb);
    final_kernel<<<MM / 256, 256, 0, stream>>>(wsb, curv_log, out);
}

// Round 6
// 91.379 us; speedup vs baseline: 1.3946x; 1.3946x over previous
//
#include <hip/hip_runtime.h>
#include <hip/hip_bf16.h>
#include <math.h>

#define MM 8192
#define CC 4096
#define DD 768
#define EPSF 1e-8f

#define BM 256
#define BN 256
#define BK 64
#define TPB 512
#define NKT (DD / BK)          // 12 K-tiles
#define NROWT (MM / BM)        // 32
#define NCOLT (CC / BN)        // 16

// ---- ws layout ----
#define XB_OFF 0
#define YB_OFF (MM * DD * 2)
#define FW_OFF (YB_OFF + CC * DD * 2)
#define S_T 0
#define T_T (MM)
#define S_L (2 * MM)
#define T_L (2 * MM + CC)
#define CA_T (2 * MM + 2 * CC)         // t_t / s_t per text row
#define POS  (CA_T + MM)
#define PART (POS + MM)                // MM * NCOLT * 2 floats (top-2 largest u)

typedef __attribute__((ext_vector_type(8))) short short8;
typedef __attribute__((ext_vector_type(4))) unsigned short u16x4;
typedef __attribute__((ext_vector_type(4))) float f32x4;

__device__ inline unsigned short f2bf(float f) {
    unsigned int u = __float_as_uint(f);
    u += 0x7FFF + ((u >> 16) & 1);   // RNE
    return (unsigned short)(u >> 16);
}

__device__ inline void gll16(const void* g, void* l) {
    __builtin_amdgcn_global_load_lds(
        (const __attribute__((address_space(1))) void*)(uintptr_t)g,
        (__attribute__((address_space(3))) void*)(unsigned)(uintptr_t)l,
        16, 0, 0);
}

#define BAR() do { __builtin_amdgcn_sched_barrier(0); __builtin_amdgcn_s_barrier(); __builtin_amdgcn_sched_barrier(0); } while (0)
#define VM8 asm volatile("s_waitcnt vmcnt(8)" ::: "memory")
#define VM4 asm volatile("s_waitcnt vmcnt(4)" ::: "memory")
#define VM0 asm volatile("s_waitcnt vmcnt(0)" ::: "memory")
#define NOPS ((void)0)

#define DSR(dst, base, off) \
    asm volatile("ds_read_b128 %0, %1 offset:%c2" : "=v"(dst) : "v"(base), "n"(off))

#define MFMA_B(a, b, c) __builtin_amdgcn_mfma_f32_16x16x32_bf16((a), (b), (c), 0, 0, 0)

// ---------------- prep+convert: per-row s,t,ca + bf16 copies ----------------
__global__ void prep_conv_kernel(const float* __restrict__ X, const float* __restrict__ Y,
                                 const float* curv_log, const float* ta_log, const float* la_log,
                                 char* __restrict__ wsb) {
    unsigned short* Xb = (unsigned short*)(wsb + XB_OFF);
    unsigned short* Yb = (unsigned short*)(wsb + YB_OFF);
    float* fws = (float*)(wsb + FW_OFF);
    int wid = threadIdx.x >> 6, lane = threadIdx.x & 63;
    int row = blockIdx.x * 4 + wid;
    float curv = __expf(curv_log[0]);
    const float* src; unsigned short* dst; float alpha; int idx; int is_text;
    if (row < MM) {
        src = X + (size_t)row * DD; dst = Xb + (size_t)row * DD;
        alpha = __expf(ta_log[0]); idx = row; is_text = 1;
    } else {
        int r = row - MM;
        src = Y + (size_t)r * DD; dst = Yb + (size_t)r * DD;
        alpha = __expf(la_log[0]); idx = r; is_text = 0;
    }
    float n2 = 0.f;
    #pragma unroll
    for (int j = 0; j < 3; ++j) {
        float4 v = *(const float4*)(src + lane * 4 + 256 * j);
        n2 += v.x * v.x + v.y * v.y + v.z * v.z + v.w * v.w;
        u16x4 o; o[0] = f2bf(v.x); o[1] = f2bf(v.y); o[2] = f2bf(v.z); o[3] = f2bf(v.w);
        *(u16x4*)(dst + lane * 4 + 256 * j) = o;
    }
    #pragma unroll
    for (int m = 32; m; m >>= 1) n2 += __shfl_xor(n2, m);
    if (lane == 0) {
        float r = sqrtf(curv) * alpha * sqrtf(n2);
        float s = alpha * sinhf(r) / fmaxf(r, EPSF);
        float tt = sqrtf(1.0f / curv + s * s * n2);
        if (is_text) {
            fws[S_T + idx] = s; fws[T_T + idx] = tt; fws[CA_T + idx] = tt / s;
        } else {
            fws[S_L + idx] = s; fws[T_L + idx] = tt;
        }
    }
}

// ---------------- pos: exact fp32 positive distance ----------------
__global__ void pos_kernel(const float* __restrict__ X, const float* __restrict__ Y,
                           const int* __restrict__ tgt, const float* curv_log,
                           char* __restrict__ wsb) {
    float* fws = (float*)(wsb + FW_OFF);
    int wid = threadIdx.x >> 6, lane = threadIdx.x & 63;
    int row = blockIdx.x * 4 + wid;
    if (row >= MM) return;
    float curv = __expf(curv_log[0]);
    int t = tgt[row];
    const float* xr = X + (size_t)row * DD;
    const float* yr = Y + (size_t)t * DD;
    float dot = 0.f;
    #pragma unroll
    for (int k = 0; k < DD / 64; ++k) dot += xr[lane + 64 * k] * yr[lane + 64 * k];
    #pragma unroll
    for (int m = 32; m; m >>= 1) dot += __shfl_xor(dot, m);
    if (lane == 0) {
        float inner = fws[S_T + row] * fws[S_L + t] * dot - fws[T_T + row] * fws[T_L + t];
        float cd = fmaxf(-curv * inner, 1.0f + EPSF);
        float d = __logf(cd + sqrtf(cd * cd - 1.0f)) * rsqrtf(curv);
        fws[POS + row] = d;
    }
}

// ---------------- main: 256x256 8-phase, row-major LDS (conflict-free), counted vmcnt ----------------
__global__ __launch_bounds__(TPB, 2) void main_kernel(
    const int* __restrict__ tgt, char* __restrict__ wsb)
{
    // region rg = (kt&1)*2 + kh; region = [row 0..255][k 0..31] row-major (64B rows) = 16KB
    __shared__ unsigned short Ald[4 * 8192];   // 64KB
    __shared__ unsigned short Bld[4 * 8192];   // 64KB
    __shared__ float red[256][4][2];           // 8KB

    const unsigned short* Xb = (const unsigned short*)(wsb + XB_OFF);
    const unsigned short* Yb = (const unsigned short*)(wsb + YB_OFF);
    float* fws = (float*)(wsb + FW_OFF);

    int tid = threadIdx.x;
    int lane = tid & 63, wid = tid >> 6;
    int wr = wid >> 2, wc = wid & 3;           // 2 row-groups x 4 col-groups
    int l15 = lane & 15, rgrp = lane >> 4;

    // XCD-bijective swizzle: 512 blocks, xcd = bid&7 owns 4 rowpanels x all 16 coltiles
    int bid = blockIdx.x;
    int pos = bid >> 3;
    int coltile = pos >> 2;                    // 0..15
    int rowpanel = (bid & 7) * 4 + (pos & 3);  // 0..31
    int rowbase = rowpanel * BM;
    int colbase = coltile * BN;

    // staging: chunk c (0..1023) -> row = c>>2, ko = c&3 (8 k-elems each); LDS off = c*16B (linear)
    // thread t stages chunks t and t+512 (row +128)
    const unsigned short* xk = Xb + (size_t)(rowbase + (tid >> 2)) * DD + ((tid & 3) * 8);
    const unsigned short* yk = Yb + (size_t)(colbase + (tid >> 2)) * DD + ((tid & 3) * 8);
    unsigned short* adst = Ald + tid * 8;
    unsigned short* bdst = Bld + tid * 8;

#define STG_A(OFF, RG) do { gll16(xk + (OFF), adst + (RG) * 8192); \
                            gll16(xk + (size_t)128 * DD + (OFF), adst + (RG) * 8192 + 4096); } while (0)
#define STG_B(OFF, RG) do { gll16(yk + (OFF), bdst + (RG) * 8192); \
                            gll16(yk + (size_t)128 * DD + (OFF), bdst + (RG) * 8192 + 4096); } while (0)

    // fragment read bases: row-major region -> lane addr = row*64 + rgrp*16 (64 lanes contiguous 1KB)
    unsigned a_base = (unsigned)(uintptr_t)(&Ald[0]) + (wr * 128 + l15) * 64 + rgrp * 16;
    unsigned b_base = (unsigned)(uintptr_t)(&Bld[0]) + (wc * 64 + l15) * 64 + rgrp * 16;

    f32x4 acc[8][4];
    #pragma unroll
    for (int a = 0; a < 8; ++a)
        #pragma unroll
        for (int b = 0; b < 4; ++b)
            acc[a][b] = (f32x4){0.f, 0.f, 0.f, 0.f};

    short8 af[4], bf[4];

#define MF16(AO) do { \
    acc[(AO)+0][0] = MFMA_B(af[0], bf[0], acc[(AO)+0][0]); \
    acc[(AO)+0][1] = MFMA_B(af[0], bf[1], acc[(AO)+0][1]); \
    acc[(AO)+0][2] = MFMA_B(af[0], bf[2], acc[(AO)+0][2]); \
    acc[(AO)+0][3] = MFMA_B(af[0], bf[3], acc[(AO)+0][3]); \
    acc[(AO)+1][0] = MFMA_B(af[1], bf[0], acc[(AO)+1][0]); \
    acc[(AO)+1][1] = MFMA_B(af[1], bf[1], acc[(AO)+1][1]); \
    acc[(AO)+1][2] = MFMA_B(af[1], bf[2], acc[(AO)+1][2]); \
    acc[(AO)+1][3] = MFMA_B(af[1], bf[3], acc[(AO)+1][3]); \
    acc[(AO)+2][0] = MFMA_B(af[2], bf[0], acc[(AO)+2][0]); \
    acc[(AO)+2][1] = MFMA_B(af[2], bf[1], acc[(AO)+2][1]); \
    acc[(AO)+2][2] = MFMA_B(af[2], bf[2], acc[(AO)+2][2]); \
    acc[(AO)+2][3] = MFMA_B(af[2], bf[3], acc[(AO)+2][3]); \
    acc[(AO)+3][0] = MFMA_B(af[3], bf[0], acc[(AO)+3][0]); \
    acc[(AO)+3][1] = MFMA_B(af[3], bf[1], acc[(AO)+3][1]); \
    acc[(AO)+3][2] = MFMA_B(af[3], bf[2], acc[(AO)+3][2]); \
    acc[(AO)+3][3] = MFMA_B(af[3], bf[3], acc[(AO)+3][3]); \
} while (0)

    // one phase: ds_reads -> stage -> [counted vmcnt] -> barrier -> lgkm(0) -> MFMA -> barrier
    // vmcnt BEFORE the barrier guarantees all waves' staged region is in LDS before the
    // phase that reads it (next phase) -- race-free counted-wait placement.
#define PHASE(RG, MH, AO, STG, W) do { \
    if ((MH) == 0) { \
        DSR(bf[0], b_base, (RG) * 16384 + 0); \
        DSR(bf[1], b_base, (RG) * 16384 + 1024); \
        DSR(bf[2], b_base, (RG) * 16384 + 2048); \
        DSR(bf[3], b_base, (RG) * 16384 + 3072); \
    } \
    DSR(af[0], a_base, (RG) * 16384 + ((MH) * 4 + 0) * 1024); \
    DSR(af[1], a_base, (RG) * 16384 + ((MH) * 4 + 1) * 1024); \
    DSR(af[2], a_base, (RG) * 16384 + ((MH) * 4 + 2) * 1024); \
    DSR(af[3], a_base, (RG) * 16384 + ((MH) * 4 + 3) * 1024); \
    STG; \
    W; \
    BAR(); \
    asm volatile("s_waitcnt lgkmcnt(0)" ::: "memory"); \
    __builtin_amdgcn_sched_barrier(0); \
    __builtin_amdgcn_s_setprio(1); \
    MF16(AO); \
    __builtin_amdgcn_s_setprio(0); \
    BAR(); \
} while (0)

    // prologue: stage rg0(A,B), rg1(A,B), rg2(A,B) = 12 loads; drain rg0
    STG_A(0, 0);  STG_B(0, 0);
    STG_A(32, 1); STG_B(32, 1);
    STG_A(64, 2); STG_B(64, 2);
    VM8;
    BAR();

    // 5 full pairs (kt = 0,2,4,6,8): vmcnt(8) at every odd phase drains exactly the
    // region consumed in the following phase (steady state: 12 in flight -> 8)
    #pragma unroll 1
    for (int kp = 0; kp < 5; ++kp) {
        PHASE(0, 0, 0, STG_A(96, 3),  NOPS);
        PHASE(0, 1, 4, STG_B(96, 3),  VM8);
        PHASE(1, 0, 0, STG_A(128, 0), NOPS);
        PHASE(1, 1, 4, STG_B(128, 0), VM8);
        PHASE(2, 0, 0, STG_A(160, 1), NOPS);
        PHASE(2, 1, 4, STG_B(160, 1), VM8);
        PHASE(3, 0, 0, STG_A(192, 2), NOPS);
        PHASE(3, 1, 4, STG_B(192, 2), VM8);
        xk += 128; yk += 128;
    }
    // tail pair (kt = 10,11): only (11,h1) left to stage; waits taper 8 -> 4 -> 0
    PHASE(0, 0, 0, STG_A(96, 3), NOPS);
    PHASE(0, 1, 4, STG_B(96, 3), VM8);
    PHASE(1, 0, 0, NOPS, NOPS);
    PHASE(1, 1, 4, NOPS, VM4);
    PHASE(2, 0, 0, NOPS, NOPS);
    PHASE(2, 1, 4, NOPS, VM0);
    PHASE(3, 0, 0, NOPS, NOPS);
    PHASE(3, 1, 4, NOPS, NOPS);

    // ---- epilogue: per-row top-2 of u = sb*dot - ca*tb (argtop2 == top2 of inner; sa>0) ----
    int colb = colbase + wc * 64 + l15;
    float sbv[4], tbv[4];
    #pragma unroll
    for (int nf = 0; nf < 4; ++nf) { sbv[nf] = fws[S_L + colb + nf * 16]; tbv[nf] = fws[T_L + colb + nf * 16]; }

    float m1[32], m2[32];
    #pragma unroll
    for (int mf = 0; mf < 8; ++mf) {
        int rw = rowbase + wr * 128 + mf * 16 + rgrp * 4;
        #pragma unroll
        for (int j = 0; j < 4; ++j) {
            float ca = fws[CA_T + rw + j];
            int tgj = tgt[rw + j];
            float a = -3.4e38f, b = -3.4e38f;
            #pragma unroll
            for (int nf = 0; nf < 4; ++nf) {
                float u = sbv[nf] * acc[mf][nf][j] - ca * tbv[nf];
                if (colb + nf * 16 == tgj) u = -3.4e38f;
                float n1 = fmaxf(a, u);
                b = fmaxf(b, fminf(a, u));
                a = n1;
            }
            m1[mf * 4 + j] = a; m2[mf * 4 + j] = b;
        }
    }
    #pragma unroll
    for (int mask = 1; mask <= 8; mask <<= 1)
        #pragma unroll
        for (int i = 0; i < 32; ++i) {
            float o1 = __shfl_xor(m1[i], mask);
            float o2 = __shfl_xor(m2[i], mask);
            float n1 = fmaxf(m1[i], o1);
            m2[i] = fmaxf(fminf(m1[i], o1), fmaxf(m2[i], o2));
            m1[i] = n1;
        }
    if (l15 == 0) {
        #pragma unroll
        for (int mf = 0; mf < 8; ++mf)
            #pragma unroll
            for (int j = 0; j < 4; ++j) {
                int rl = wr * 128 + mf * 16 + rgrp * 4 + j;
                red[rl][wc][0] = m1[mf * 4 + j];
                red[rl][wc][1] = m2[mf * 4 + j];
            }
    }
    __syncthreads();
    if (tid < 256) {
        float p1 = -3.4e38f, p2 = -3.4e38f;
        #pragma unroll
        for (int g = 0; g < 4; ++g) {
            float a1 = red[tid][g][0], a2 = red[tid][g][1];
            float n1 = fmaxf(p1, a1);
            p2 = fmaxf(fminf(p1, a1), fmaxf(p2, a2));
            p1 = n1;
        }
        int row = rowbase + tid;
        fws[PART + ((size_t)row * NCOLT + coltile) * 2 + 0] = p1;
        fws[PART + ((size_t)row * NCOLT + coltile) * 2 + 1] = p2;
    }
}

// ---------------- final: merge partials, arccosh on winners, loss ----------------
__global__ void final_kernel(const char* __restrict__ wsb, const float* __restrict__ curv_log,
                             float* __restrict__ out) {
    const float* fws = (const float*)(wsb + FW_OFF);
    int row = blockIdx.x * 256 + threadIdx.x;
    if (row >= MM) return;
    float curv = __expf(curv_log[0]);
    float rsc = rsqrtf(curv);
    const float* p = fws + PART + (size_t)row * (NCOLT * 2);
    float p1 = -3.4e38f, p2 = -3.4e38f;
    #pragma unroll
    for (int s = 0; s < NCOLT; ++s) {
        float a1 = p[s * 2], a2 = p[s * 2 + 1];
        float n1 = fmaxf(p1, a1);
        p2 = fmaxf(fminf(p1, a1), fmaxf(p2, a2));
        p1 = n1;
    }
    float sa = fws[S_T + row];
    float i1 = sa * p1, i2 = sa * p2;          // back to Lorentz inner
    float cd1 = fmaxf(-curv * i1, 1.0f + EPSF);
    float d1 = __logf(cd1 + sqrtf(cd1 * cd1 - 1.0f)) * rsc;
    float cd2 = fmaxf(-curv * i2, 1.0f + EPSF);
    float d2 = __logf(cd2 + sqrtf(cd2 * cd2 - 1.0f)) * rsc;
    float dp = fws[POS + row];
    float denom = __expf(-dp) + __expf(-d1) + __expf(-d2);
    out[row] = __logf(denom) + dp;
}

extern "C" void kernel_launch(void* const* d_in, const int* in_sizes, int n_in,
                              void* d_out, int out_size, void* d_ws, size_t ws_size,
                              hipStream_t stream) {
    const float* X = (const float*)d_in[0];
    const float* Y = (const float*)d_in[1];
    const int* tgt = (const int*)d_in[2];
    const float* curv_log = (const float*)d_in[3];
    const float* ta_log = (const float*)d_in[4];
    const float* la_log = (const float*)d_in[5];
    char* wsb = (char*)d_ws;
    float* out = (float*)d_out;

    prep_conv_kernel<<<(MM + CC) / 4, 256, 0, stream>>>(X, Y, curv_log, ta_log, la_log, wsb);
    pos_kernel<<<MM / 4, 256, 0, stream>>>(X, Y, tgt, curv_log, wsb);
    main_kernel<<<NROWT * NCOLT, TPB, 0, stream>>>(tgt, wsb);
    final_kernel<<<MM / 256, 256, 0, stream>>>(wsb, curv_log, out);
}

// Round 7
// 89.166 us; speedup vs baseline: 1.4292x; 1.0248x over previous
//
#include <hip/hip_runtime.h>
#include <hip/hip_bf16.h>
#include <math.h>

#define MM 8192
#define CC 4096
#define DD 768
#define EPSF 1e-8f

#define BM 256
#define BN 256
#define BK 64
#define TPB 512
#define NKT (DD / BK)          // 12 K-tiles
#define NROWT (MM / BM)        // 32
#define NCOLT (CC / BN)        // 16

// ---- ws layout ----
#define XB_OFF 0
#define YB_OFF (MM * DD * 2)
#define FW_OFF (YB_OFF + CC * DD * 2)
#define S_T 0
#define T_T (MM)
#define S_L (2 * MM)
#define T_L (2 * MM + CC)
#define CA_T (2 * MM + 2 * CC)         // t_t / s_t per text row
#define POS  (CA_T + MM)
#define PART (POS + MM)                // MM * NCOLT * 2 floats (top-2 largest u)

typedef __attribute__((ext_vector_type(8))) short short8;
typedef __attribute__((ext_vector_type(4))) unsigned short u16x4;
typedef __attribute__((ext_vector_type(4))) float f32x4;

__device__ inline unsigned short f2bf(float f) {
    unsigned int u = __float_as_uint(f);
    u += 0x7FFF + ((u >> 16) & 1);   // RNE
    return (unsigned short)(u >> 16);
}

__device__ inline void gll16(const void* g, void* l) {
    __builtin_amdgcn_global_load_lds(
        (const __attribute__((address_space(1))) void*)(uintptr_t)g,
        (__attribute__((address_space(3))) void*)(unsigned)(uintptr_t)l,
        16, 0, 0);
}

#define BAR() do { __builtin_amdgcn_sched_barrier(0); __builtin_amdgcn_s_barrier(); __builtin_amdgcn_sched_barrier(0); } while (0)
#define VM8 asm volatile("s_waitcnt vmcnt(8)" ::: "memory")
#define VM4 asm volatile("s_waitcnt vmcnt(4)" ::: "memory")
#define VM0 asm volatile("s_waitcnt vmcnt(0)" ::: "memory")
#define NOPS ((void)0)

#define DSR(dst, base, off) \
    asm volatile("ds_read_b128 %0, %1 offset:%c2" : "=v"(dst) : "v"(base), "n"(off))

#define MFMA_B(a, b, c) __builtin_amdgcn_mfma_f32_16x16x32_bf16((a), (b), (c), 0, 0, 0)

// ---------------- prep+convert: per-row s,t,ca + bf16 copies ----------------
__global__ void prep_conv_kernel(const float* __restrict__ X, const float* __restrict__ Y,
                                 const float* curv_log, const float* ta_log, const float* la_log,
                                 char* __restrict__ wsb) {
    unsigned short* Xb = (unsigned short*)(wsb + XB_OFF);
    unsigned short* Yb = (unsigned short*)(wsb + YB_OFF);
    float* fws = (float*)(wsb + FW_OFF);
    int wid = threadIdx.x >> 6, lane = threadIdx.x & 63;
    int row = blockIdx.x * 4 + wid;
    float curv = __expf(curv_log[0]);
    const float* src; unsigned short* dst; float alpha; int idx; int is_text;
    if (row < MM) {
        src = X + (size_t)row * DD; dst = Xb + (size_t)row * DD;
        alpha = __expf(ta_log[0]); idx = row; is_text = 1;
    } else {
        int r = row - MM;
        src = Y + (size_t)r * DD; dst = Yb + (size_t)r * DD;
        alpha = __expf(la_log[0]); idx = r; is_text = 0;
    }
    float n2 = 0.f;
    #pragma unroll
    for (int j = 0; j < 3; ++j) {
        float4 v = *(const float4*)(src + lane * 4 + 256 * j);
        n2 += v.x * v.x + v.y * v.y + v.z * v.z + v.w * v.w;
        u16x4 o; o[0] = f2bf(v.x); o[1] = f2bf(v.y); o[2] = f2bf(v.z); o[3] = f2bf(v.w);
        *(u16x4*)(dst + lane * 4 + 256 * j) = o;
    }
    #pragma unroll
    for (int m = 32; m; m >>= 1) n2 += __shfl_xor(n2, m);
    if (lane == 0) {
        float r = sqrtf(curv) * alpha * sqrtf(n2);
        float s = alpha * sinhf(r) / fmaxf(r, EPSF);
        float tt = sqrtf(1.0f / curv + s * s * n2);
        if (is_text) {
            fws[S_T + idx] = s; fws[T_T + idx] = tt; fws[CA_T + idx] = tt / s;
        } else {
            fws[S_L + idx] = s; fws[T_L + idx] = tt;
        }
    }
}

// ---------------- pos: exact fp32 positive distance ----------------
__global__ void pos_kernel(const float* __restrict__ X, const float* __restrict__ Y,
                           const int* __restrict__ tgt, const float* curv_log,
                           char* __restrict__ wsb) {
    float* fws = (float*)(wsb + FW_OFF);
    int wid = threadIdx.x >> 6, lane = threadIdx.x & 63;
    int row = blockIdx.x * 4 + wid;
    if (row >= MM) return;
    float curv = __expf(curv_log[0]);
    int t = tgt[row];
    const float* xr = X + (size_t)row * DD;
    const float* yr = Y + (size_t)t * DD;
    float dot = 0.f;
    #pragma unroll
    for (int k = 0; k < DD / 64; ++k) dot += xr[lane + 64 * k] * yr[lane + 64 * k];
    #pragma unroll
    for (int m = 32; m; m >>= 1) dot += __shfl_xor(dot, m);
    if (lane == 0) {
        float inner = fws[S_T + row] * fws[S_L + t] * dot - fws[T_T + row] * fws[T_L + t];
        float cd = fmaxf(-curv * inner, 1.0f + EPSF);
        float d = __logf(cd + sqrtf(cd * cd - 1.0f)) * rsqrtf(curv);
        fws[POS + row] = d;
    }
}

// ---------------- main: 256x256 8-phase, XOR-swizzled row-major LDS, counted vmcnt ----------------
__global__ __launch_bounds__(TPB, 2) void main_kernel(
    const int* __restrict__ tgt, char* __restrict__ wsb)
{
    // region rg = (kt&1)*2 + kh; region = [row 0..255][k-slot 0..3] 64B rows, 16KB.
    // XOR swizzle: byte = row*64 + (slot*16 ^ ((row>>1)&3)<<4)  -> 2-way banks on ds_read_b128.
    // LDS writes stay linear (global_load_lds); global SOURCE is pre-permuted to compensate.
    __shared__ unsigned short Ald[4 * 8192];   // 64KB
    __shared__ unsigned short Bld[4 * 8192];   // 64KB
    __shared__ float red[256][4][2];           // 8KB

    const unsigned short* Xb = (const unsigned short*)(wsb + XB_OFF);
    const unsigned short* Yb = (const unsigned short*)(wsb + YB_OFF);
    float* fws = (float*)(wsb + FW_OFF);

    int tid = threadIdx.x;
    int lane = tid & 63, wid = tid >> 6;
    int wr = wid >> 2, wc = wid & 3;           // 2 row-groups x 4 col-groups
    int l15 = lane & 15, rgrp = lane >> 4;

    // XCD-bijective swizzle: 512 blocks, xcd = bid&7 owns 4 rowpanels x all 16 coltiles
    int bid = blockIdx.x;
    int pos = bid >> 3;
    int coltile = pos >> 2;                    // 0..15
    int rowpanel = (bid & 7) * 4 + (pos & 3);  // 0..31
    int rowbase = rowpanel * BM;
    int colbase = coltile * BN;

    // staging: LDS slot t (16B, linear) holds row = t>>2, k-octet = (t&3) ^ ((t>>3)&3)
    // (inverse of the read-side XOR; (t+512) gives same k-octet, row+128)
    int ko_src = ((tid & 3) ^ ((tid >> 3) & 3)) * 8;
    const unsigned short* xk = Xb + (size_t)(rowbase + (tid >> 2)) * DD + ko_src;
    const unsigned short* yk = Yb + (size_t)(colbase + (tid >> 2)) * DD + ko_src;
    unsigned short* adst = Ald + tid * 8;
    unsigned short* bdst = Bld + tid * 8;

#define STG_A(OFF, RG) do { gll16(xk + (OFF), adst + (RG) * 8192); \
                            gll16(xk + (size_t)128 * DD + (OFF), adst + (RG) * 8192 + 4096); } while (0)
#define STG_B(OFF, RG) do { gll16(yk + (OFF), bdst + (RG) * 8192); \
                            gll16(yk + (size_t)128 * DD + (OFF), bdst + (RG) * 8192 + 4096); } while (0)

    // fragment read bases with read-side XOR folded in (per-lane constant; all loop
    // offsets are row-aligned multiples of 1024 so immediates are unaffected)
    unsigned a_base = (unsigned)(uintptr_t)(&Ald[0]) + (wr * 128 + l15) * 64
                      + ((rgrp * 16) ^ (((l15 >> 1) & 3) << 4));
    unsigned b_base = (unsigned)(uintptr_t)(&Bld[0]) + (wc * 64 + l15) * 64
                      + ((rgrp * 16) ^ (((l15 >> 1) & 3) << 4));

    f32x4 acc[8][4];
    #pragma unroll
    for (int a = 0; a < 8; ++a)
        #pragma unroll
        for (int b = 0; b < 4; ++b)
            acc[a][b] = (f32x4){0.f, 0.f, 0.f, 0.f};

    short8 af[4], bf[4];

#define MF16(AO) do { \
    acc[(AO)+0][0] = MFMA_B(af[0], bf[0], acc[(AO)+0][0]); \
    acc[(AO)+0][1] = MFMA_B(af[0], bf[1], acc[(AO)+0][1]); \
    acc[(AO)+0][2] = MFMA_B(af[0], bf[2], acc[(AO)+0][2]); \
    acc[(AO)+0][3] = MFMA_B(af[0], bf[3], acc[(AO)+0][3]); \
    acc[(AO)+1][0] = MFMA_B(af[1], bf[0], acc[(AO)+1][0]); \
    acc[(AO)+1][1] = MFMA_B(af[1], bf[1], acc[(AO)+1][1]); \
    acc[(AO)+1][2] = MFMA_B(af[1], bf[2], acc[(AO)+1][2]); \
    acc[(AO)+1][3] = MFMA_B(af[1], bf[3], acc[(AO)+1][3]); \
    acc[(AO)+2][0] = MFMA_B(af[2], bf[0], acc[(AO)+2][0]); \
    acc[(AO)+2][1] = MFMA_B(af[2], bf[1], acc[(AO)+2][1]); \
    acc[(AO)+2][2] = MFMA_B(af[2], bf[2], acc[(AO)+2][2]); \
    acc[(AO)+2][3] = MFMA_B(af[2], bf[3], acc[(AO)+2][3]); \
    acc[(AO)+3][0] = MFMA_B(af[3], bf[0], acc[(AO)+3][0]); \
    acc[(AO)+3][1] = MFMA_B(af[3], bf[1], acc[(AO)+3][1]); \
    acc[(AO)+3][2] = MFMA_B(af[3], bf[2], acc[(AO)+3][2]); \
    acc[(AO)+3][3] = MFMA_B(af[3], bf[3], acc[(AO)+3][3]); \
} while (0)

#define PHASE(RG, MH, AO, STG, W) do { \
    if ((MH) == 0) { \
        DSR(bf[0], b_base, (RG) * 16384 + 0); \
        DSR(bf[1], b_base, (RG) * 16384 + 1024); \
        DSR(bf[2], b_base, (RG) * 16384 + 2048); \
        DSR(bf[3], b_base, (RG) * 16384 + 3072); \
    } \
    DSR(af[0], a_base, (RG) * 16384 + ((MH) * 4 + 0) * 1024); \
    DSR(af[1], a_base, (RG) * 16384 + ((MH) * 4 + 1) * 1024); \
    DSR(af[2], a_base, (RG) * 16384 + ((MH) * 4 + 2) * 1024); \
    DSR(af[3], a_base, (RG) * 16384 + ((MH) * 4 + 3) * 1024); \
    STG; \
    W; \
    BAR(); \
    asm volatile("s_waitcnt lgkmcnt(0)" ::: "memory"); \
    __builtin_amdgcn_sched_barrier(0); \
    __builtin_amdgcn_s_setprio(1); \
    MF16(AO); \
    __builtin_amdgcn_s_setprio(0); \
    BAR(); \
} while (0)

    // prologue: stage rg0(A,B), rg1(A,B), rg2(A,B) = 12 loads; drain rg0
    STG_A(0, 0);  STG_B(0, 0);
    STG_A(32, 1); STG_B(32, 1);
    STG_A(64, 2); STG_B(64, 2);
    VM8;
    BAR();

    // 5 full pairs (kt = 0,2,4,6,8)
    #pragma unroll 1
    for (int kp = 0; kp < 5; ++kp) {
        PHASE(0, 0, 0, STG_A(96, 3),  NOPS);
        PHASE(0, 1, 4, STG_B(96, 3),  VM8);
        PHASE(1, 0, 0, STG_A(128, 0), NOPS);
        PHASE(1, 1, 4, STG_B(128, 0), VM8);
        PHASE(2, 0, 0, STG_A(160, 1), NOPS);
        PHASE(2, 1, 4, STG_B(160, 1), VM8);
        PHASE(3, 0, 0, STG_A(192, 2), NOPS);
        PHASE(3, 1, 4, STG_B(192, 2), VM8);
        xk += 128; yk += 128;
    }
    // tail pair (kt = 10,11)
    PHASE(0, 0, 0, STG_A(96, 3), NOPS);
    PHASE(0, 1, 4, STG_B(96, 3), VM8);
    PHASE(1, 0, 0, NOPS, NOPS);
    PHASE(1, 1, 4, NOPS, VM4);
    PHASE(2, 0, 0, NOPS, NOPS);
    PHASE(2, 1, 4, NOPS, VM0);
    PHASE(3, 0, 0, NOPS, NOPS);
    PHASE(3, 1, 4, NOPS, NOPS);

    // ---- epilogue: per-row top-2 of u = sb*dot - ca*tb (argtop2 == top2 of inner; sa>0) ----
    int colb = colbase + wc * 64 + l15;
    float sbv[4], tbv[4];
    #pragma unroll
    for (int nf = 0; nf < 4; ++nf) { sbv[nf] = fws[S_L + colb + nf * 16]; tbv[nf] = fws[T_L + colb + nf * 16]; }

    float m1[32], m2[32];
    #pragma unroll
    for (int mf = 0; mf < 8; ++mf) {
        int rw = rowbase + wr * 128 + mf * 16 + rgrp * 4;
        #pragma unroll
        for (int j = 0; j < 4; ++j) {
            float ca = fws[CA_T + rw + j];
            int tgj = tgt[rw + j];
            float a = -3.4e38f, b = -3.4e38f;
            #pragma unroll
            for (int nf = 0; nf < 4; ++nf) {
                float u = sbv[nf] * acc[mf][nf][j] - ca * tbv[nf];
                if (colb + nf * 16 == tgj) u = -3.4e38f;
                float n1 = fmaxf(a, u);
                b = fmaxf(b, fminf(a, u));
                a = n1;
            }
            m1[mf * 4 + j] = a; m2[mf * 4 + j] = b;
        }
    }
    #pragma unroll
    for (int mask = 1; mask <= 8; mask <<= 1)
        #pragma unroll
        for (int i = 0; i < 32; ++i) {
            float o1 = __shfl_xor(m1[i], mask);
            float o2 = __shfl_xor(m2[i], mask);
            float n1 = fmaxf(m1[i], o1);
            m2[i] = fmaxf(fminf(m1[i], o1), fmaxf(m2[i], o2));
            m1[i] = n1;
        }
    if (l15 == 0) {
        #pragma unroll
        for (int mf = 0; mf < 8; ++mf)
            #pragma unroll
            for (int j = 0; j < 4; ++j) {
                int rl = wr * 128 + mf * 16 + rgrp * 4 + j;
                red[rl][wc][0] = m1[mf * 4 + j];
                red[rl][wc][1] = m2[mf * 4 + j];
            }
    }
    __syncthreads();
    if (tid < 256) {
        float p1 = -3.4e38f, p2 = -3.4e38f;
        #pragma unroll
        for (int g = 0; g < 4; ++g) {
            float a1 = red[tid][g][0], a2 = red[tid][g][1];
            float n1 = fmaxf(p1, a1);
            p2 = fmaxf(fminf(p1, a1), fmaxf(p2, a2));
            p1 = n1;
        }
        int row = rowbase + tid;
        fws[PART + ((size_t)row * NCOLT + coltile) * 2 + 0] = p1;
        fws[PART + ((size_t)row * NCOLT + coltile) * 2 + 1] = p2;
    }
}

// ---------------- final: merge partials, arccosh on winners, loss ----------------
__global__ void final_kernel(const char* __restrict__ wsb, const float* __restrict__ curv_log,
                             float* __restrict__ out) {
    const float* fws = (const float*)(wsb + FW_OFF);
    int row = blockIdx.x * 256 + threadIdx.x;
    if (row >= MM) return;
    float curv = __expf(curv_log[0]);
    float rsc = rsqrtf(curv);
    const float* p = fws + PART + (size_t)row * (NCOLT * 2);
    float p1 = -3.4e38f, p2 = -3.4e38f;
    #pragma unroll
    for (int s = 0; s < NCOLT; ++s) {
        float a1 = p[s * 2], a2 = p[s * 2 + 1];
        float n1 = fmaxf(p1, a1);
        p2 = fmaxf(fminf(p1, a1), fmaxf(p2, a2));
        p1 = n1;
    }
    float sa = fws[S_T + row];
    float i1 = sa * p1, i2 = sa * p2;          // back to Lorentz inner
    float cd1 = fmaxf(-curv * i1, 1.0f + EPSF);
    float d1 = __logf(cd1 + sqrtf(cd1 * cd1 - 1.0f)) * rsc;
    float cd2 = fmaxf(-curv * i2, 1.0f + EPSF);
    float d2 = __logf(cd2 + sqrtf(cd2 * cd2 - 1.0f)) * rsc;
    float dp = fws[POS + row];
    float denom = __expf(-dp) + __expf(-d1) + __expf(-d2);
    out[row] = __logf(denom) + dp;
}

extern "C" void kernel_launch(void* const* d_in, const int* in_sizes, int n_in,
                              void* d_out, int out_size, void* d_ws, size_t ws_size,
                              hipStream_t stream) {
    const float* X = (const float*)d_in[0];
    const float* Y = (const float*)d_in[1];
    const int* tgt = (const int*)d_in[2];
    const float* curv_log = (const float*)d_in[3];
    const float* ta_log = (const float*)d_in[4];
    const float* la_log = (const float*)d_in[5];
    char* wsb = (char*)d_ws;
    float* out = (float*)d_out;

    prep_conv_kernel<<<(MM + CC) / 4, 256, 0, stream>>>(X, Y, curv_log, ta_log, la_log, wsb);
    pos_kernel<<<MM / 4, 256, 0, stream>>>(X, Y, tgt, curv_log, wsb);
    main_kernel<<<NROWT * NCOLT, TPB, 0, stream>>>(tgt, wsb);
    final_kernel<<<MM / 256, 256, 0, stream>>>(wsb, curv_log, out);
}

// Round 8
// 88.581 us; speedup vs baseline: 1.4387x; 1.0066x over previous
//
#include <hip/hip_runtime.h>
#include <hip/hip_bf16.h>
#include <math.h>

#define MM 8192
#define CC 4096
#define DD 768
#define EPSF 1e-8f

#define BM 256
#define BN 256
#define BK 64
#define TPB 512
#define NKT (DD / BK)          // 12 K-tiles
#define NROWT (MM / BM)        // 32
#define NCOLT (CC / BN)        // 16

// ---- ws layout ----
#define XB_OFF 0
#define YB_OFF (MM * DD * 2)
#define FW_OFF (YB_OFF + CC * DD * 2)
#define S_T 0
#define T_T (MM)
#define S_L (2 * MM)
#define T_L (2 * MM + CC)
#define CA_T (2 * MM + 2 * CC)         // t_t / s_t per text row
#define POS  (CA_T + MM)
#define PART (POS + MM)                // MM * NCOLT * 2 floats (top-2 largest u)

typedef __attribute__((ext_vector_type(8))) short short8;
typedef __attribute__((ext_vector_type(4))) unsigned short u16x4;
typedef __attribute__((ext_vector_type(4))) float f32x4;

__device__ inline unsigned short f2bf(float f) {
    unsigned int u = __float_as_uint(f);
    u += 0x7FFF + ((u >> 16) & 1);   // RNE
    return (unsigned short)(u >> 16);
}

__device__ inline void gll16(const void* g, void* l) {
    __builtin_amdgcn_global_load_lds(
        (const __attribute__((address_space(1))) void*)(uintptr_t)g,
        (__attribute__((address_space(3))) void*)(unsigned)(uintptr_t)l,
        16, 0, 0);
}

#define BAR() do { __builtin_amdgcn_sched_barrier(0); __builtin_amdgcn_s_barrier(); __builtin_amdgcn_sched_barrier(0); } while (0)
#define VM8 asm volatile("s_waitcnt vmcnt(8)" ::: "memory")
#define VM6 asm volatile("s_waitcnt vmcnt(6)" ::: "memory")
#define VM4 asm volatile("s_waitcnt vmcnt(4)" ::: "memory")
#define VM0 asm volatile("s_waitcnt vmcnt(0)" ::: "memory")
#define NOPS ((void)0)

#define DSR(dst, base, off) \
    asm volatile("ds_read_b128 %0, %1 offset:%c2" : "=v"(dst) : "v"(base), "n"(off))

#define MFMA_B(a, b, c) __builtin_amdgcn_mfma_f32_16x16x32_bf16((a), (b), (c), 0, 0, 0)

// ---------------- prep+convert: per-row s,t,ca + bf16 copies ----------------
__global__ void prep_conv_kernel(const float* __restrict__ X, const float* __restrict__ Y,
                                 const float* curv_log, const float* ta_log, const float* la_log,
                                 char* __restrict__ wsb) {
    unsigned short* Xb = (unsigned short*)(wsb + XB_OFF);
    unsigned short* Yb = (unsigned short*)(wsb + YB_OFF);
    float* fws = (float*)(wsb + FW_OFF);
    int wid = threadIdx.x >> 6, lane = threadIdx.x & 63;
    int row = blockIdx.x * 4 + wid;
    float curv = __expf(curv_log[0]);
    const float* src; unsigned short* dst; float alpha; int idx; int is_text;
    if (row < MM) {
        src = X + (size_t)row * DD; dst = Xb + (size_t)row * DD;
        alpha = __expf(ta_log[0]); idx = row; is_text = 1;
    } else {
        int r = row - MM;
        src = Y + (size_t)r * DD; dst = Yb + (size_t)r * DD;
        alpha = __expf(la_log[0]); idx = r; is_text = 0;
    }
    float n2 = 0.f;
    #pragma unroll
    for (int j = 0; j < 3; ++j) {
        float4 v = *(const float4*)(src + lane * 4 + 256 * j);
        n2 += v.x * v.x + v.y * v.y + v.z * v.z + v.w * v.w;
        u16x4 o; o[0] = f2bf(v.x); o[1] = f2bf(v.y); o[2] = f2bf(v.z); o[3] = f2bf(v.w);
        *(u16x4*)(dst + lane * 4 + 256 * j) = o;
    }
    #pragma unroll
    for (int m = 32; m; m >>= 1) n2 += __shfl_xor(n2, m);
    if (lane == 0) {
        float r = sqrtf(curv) * alpha * sqrtf(n2);
        float s = alpha * sinhf(r) / fmaxf(r, EPSF);
        float tt = sqrtf(1.0f / curv + s * s * n2);
        if (is_text) {
            fws[S_T + idx] = s; fws[T_T + idx] = tt; fws[CA_T + idx] = tt / s;
        } else {
            fws[S_L + idx] = s; fws[T_L + idx] = tt;
        }
    }
}

// ---------------- pos: exact fp32 positive distance ----------------
__global__ void pos_kernel(const float* __restrict__ X, const float* __restrict__ Y,
                           const int* __restrict__ tgt, const float* curv_log,
                           char* __restrict__ wsb) {
    float* fws = (float*)(wsb + FW_OFF);
    int wid = threadIdx.x >> 6, lane = threadIdx.x & 63;
    int row = blockIdx.x * 4 + wid;
    if (row >= MM) return;
    float curv = __expf(curv_log[0]);
    int t = tgt[row];
    const float* xr = X + (size_t)row * DD;
    const float* yr = Y + (size_t)t * DD;
    float dot = 0.f;
    #pragma unroll
    for (int k = 0; k < DD / 64; ++k) dot += xr[lane + 64 * k] * yr[lane + 64 * k];
    #pragma unroll
    for (int m = 32; m; m >>= 1) dot += __shfl_xor(dot, m);
    if (lane == 0) {
        float inner = fws[S_T + row] * fws[S_L + t] * dot - fws[T_T + row] * fws[T_L + t];
        float cd = fmaxf(-curv * inner, 1.0f + EPSF);
        float d = __logf(cd + sqrtf(cd * cd - 1.0f)) * rsqrtf(curv);
        fws[POS + row] = d;
    }
}

// ---------------- main: 256x256 8-phase, reg-double-buffered frags (reads overlap MFMA) ----------------
__global__ __launch_bounds__(TPB) void main_kernel(
    const int* __restrict__ tgt, char* __restrict__ wsb)
{
    // region rg = (kt&1)*2 + kh; [row 0..255][k-slot 0..3], 64B rows, XOR-swizzled (R6), 16KB each.
    __shared__ unsigned short Ald[4 * 8192];   // 64KB
    __shared__ unsigned short Bld[4 * 8192];   // 64KB
    __shared__ float red[256][4][2];           // 8KB

    const unsigned short* Xb = (const unsigned short*)(wsb + XB_OFF);
    const unsigned short* Yb = (const unsigned short*)(wsb + YB_OFF);
    float* fws = (float*)(wsb + FW_OFF);

    int tid = threadIdx.x;
    int lane = tid & 63, wid = tid >> 6;
    int wr = wid >> 2, wc = wid & 3;           // 2 row-groups x 4 col-groups
    int l15 = lane & 15, rgrp = lane >> 4;

    // XCD-bijective swizzle: 512 blocks
    int bid = blockIdx.x;
    int pos = bid >> 3;
    int coltile = pos >> 2;                    // 0..15
    int rowpanel = (bid & 7) * 4 + (pos & 3);  // 0..31
    int rowbase = rowpanel * BM;
    int colbase = coltile * BN;

    // staging: LDS slot t (16B, linear) holds row = t>>2, k-octet = (t&3) ^ ((t>>3)&3)
    int ko_src = ((tid & 3) ^ ((tid >> 3) & 3)) * 8;
    const unsigned short* xk = Xb + (size_t)(rowbase + (tid >> 2)) * DD + ko_src;
    const unsigned short* yk = Yb + (size_t)(colbase + (tid >> 2)) * DD + ko_src;
    unsigned short* adst = Ald + tid * 8;
    unsigned short* bdst = Bld + tid * 8;

#define STG_A(OFF, RG) do { gll16(xk + (OFF), adst + (RG) * 8192); \
                            gll16(xk + (size_t)128 * DD + (OFF), adst + (RG) * 8192 + 4096); } while (0)
#define STG_B(OFF, RG) do { gll16(yk + (OFF), bdst + (RG) * 8192); \
                            gll16(yk + (size_t)128 * DD + (OFF), bdst + (RG) * 8192 + 4096); } while (0)

    // fragment read bases with read-side XOR folded in (per-lane constant)
    unsigned a_base = (unsigned)(uintptr_t)(&Ald[0]) + (wr * 128 + l15) * 64
                      + ((rgrp * 16) ^ (((l15 >> 1) & 3) << 4));
    unsigned b_base = (unsigned)(uintptr_t)(&Bld[0]) + (wc * 64 + l15) * 64
                      + ((rgrp * 16) ^ (((l15 >> 1) & 3) << 4));

    f32x4 acc[8][4];
    #pragma unroll
    for (int a = 0; a < 8; ++a)
        #pragma unroll
        for (int b = 0; b < 4; ++b)
            acc[a][b] = (f32x4){0.f, 0.f, 0.f, 0.f};

    // double-buffered fragment registers: afE/afO alternate per phase; bf0/bf1 per 2 phases
    short8 afE[4], afO[4], bf0[4], bf1[4];

#define LDA(S, RG, MH) do { \
    DSR(S[0], a_base, (RG) * 16384 + ((MH) * 4 + 0) * 1024); \
    DSR(S[1], a_base, (RG) * 16384 + ((MH) * 4 + 1) * 1024); \
    DSR(S[2], a_base, (RG) * 16384 + ((MH) * 4 + 2) * 1024); \
    DSR(S[3], a_base, (RG) * 16384 + ((MH) * 4 + 3) * 1024); } while (0)
#define LDB(S, RG) do { \
    DSR(S[0], b_base, (RG) * 16384 + 0); \
    DSR(S[1], b_base, (RG) * 16384 + 1024); \
    DSR(S[2], b_base, (RG) * 16384 + 2048); \
    DSR(S[3], b_base, (RG) * 16384 + 3072); } while (0)

#define MF16(AF, BF, AO) do { \
    acc[(AO)+0][0] = MFMA_B(AF[0], BF[0], acc[(AO)+0][0]); \
    acc[(AO)+0][1] = MFMA_B(AF[0], BF[1], acc[(AO)+0][1]); \
    acc[(AO)+0][2] = MFMA_B(AF[0], BF[2], acc[(AO)+0][2]); \
    acc[(AO)+0][3] = MFMA_B(AF[0], BF[3], acc[(AO)+0][3]); \
    acc[(AO)+1][0] = MFMA_B(AF[1], BF[0], acc[(AO)+1][0]); \
    acc[(AO)+1][1] = MFMA_B(AF[1], BF[1], acc[(AO)+1][1]); \
    acc[(AO)+1][2] = MFMA_B(AF[1], BF[2], acc[(AO)+1][2]); \
    acc[(AO)+1][3] = MFMA_B(AF[1], BF[3], acc[(AO)+1][3]); \
    acc[(AO)+2][0] = MFMA_B(AF[2], BF[0], acc[(AO)+2][0]); \
    acc[(AO)+2][1] = MFMA_B(AF[2], BF[1], acc[(AO)+2][1]); \
    acc[(AO)+2][2] = MFMA_B(AF[2], BF[2], acc[(AO)+2][2]); \
    acc[(AO)+2][3] = MFMA_B(AF[2], BF[3], acc[(AO)+2][3]); \
    acc[(AO)+3][0] = MFMA_B(AF[3], BF[0], acc[(AO)+3][0]); \
    acc[(AO)+3][1] = MFMA_B(AF[3], BF[1], acc[(AO)+3][1]); \
    acc[(AO)+3][2] = MFMA_B(AF[3], BF[2], acc[(AO)+3][2]); \
    acc[(AO)+3][3] = MFMA_B(AF[3], BF[3], acc[(AO)+3][3]); \
} while (0)

    // phase: [reads for NEXT phase] [stage] [counted vmcnt] BAR [counted lgkm: waits THIS
    // phase's frags (issued last phase); DS completes in-order per wave] MFMA BAR
#define PH(LD, STG, W, LGN, MF) do { \
    LD; \
    STG; \
    W; \
    BAR(); \
    asm volatile("s_waitcnt lgkmcnt(" #LGN ")" ::: "memory"); \
    __builtin_amdgcn_sched_barrier(0); \
    __builtin_amdgcn_s_setprio(1); \
    MF; \
    __builtin_amdgcn_s_setprio(0); \
    BAR(); \
} while (0)

    // prologue: stage rg0,rg1,rg2 (12 loads); drain rg0; preload phase-0 fragments
    STG_A(0, 0);  STG_B(0, 0);
    STG_A(32, 1); STG_B(32, 1);
    STG_A(64, 2); STG_B(64, 2);
    VM8;
    BAR();
    LDB(bf0, 0); LDA(afE, 0, 0);   // 8 reads for phase 0

    // 5 full pairs (kt = 0,2,4,6,8)
    #pragma unroll 1
    for (int kp = 0; kp < 5; ++kp) {
        PH(LDA(afO, 0, 1),               STG_A(96, 3),  VM6, 4, MF16(afE, bf0, 0));
        PH(LDB(bf1, 1); LDA(afE, 1, 0),  STG_B(96, 3),  VM6, 8, MF16(afO, bf0, 4));
        PH(LDA(afO, 1, 1),               STG_A(128, 0), VM6, 4, MF16(afE, bf1, 0));
        PH(LDB(bf0, 2); LDA(afE, 2, 0),  STG_B(128, 0), VM6, 8, MF16(afO, bf1, 4));
        PH(LDA(afO, 2, 1),               STG_A(160, 1), VM6, 4, MF16(afE, bf0, 0));
        PH(LDB(bf1, 3); LDA(afE, 3, 0),  STG_B(160, 1), VM6, 8, MF16(afO, bf0, 4));
        PH(LDA(afO, 3, 1),               STG_A(192, 2), VM6, 4, MF16(afE, bf1, 0));
        PH(LDB(bf0, 0); LDA(afE, 0, 0),  STG_B(192, 2), VM6, 8, MF16(afO, bf1, 4));
        xk += 128; yk += 128;
    }
    // tail pair (kt = 10,11): stage only (11,h1); waits taper
    PH(LDA(afO, 0, 1),               STG_A(96, 3), VM6, 4, MF16(afE, bf0, 0));
    PH(LDB(bf1, 1); LDA(afE, 1, 0),  STG_B(96, 3), VM6, 8, MF16(afO, bf0, 4));
    PH(LDA(afO, 1, 1),               NOPS, VM4, 4, MF16(afE, bf1, 0));
    PH(LDB(bf0, 2); LDA(afE, 2, 0),  NOPS, VM0, 8, MF16(afO, bf1, 4));
    PH(LDA(afO, 2, 1),               NOPS, NOPS, 4, MF16(afE, bf0, 0));
    PH(LDB(bf1, 3); LDA(afE, 3, 0),  NOPS, NOPS, 8, MF16(afO, bf0, 4));
    PH(LDA(afO, 3, 1),               NOPS, NOPS, 4, MF16(afE, bf1, 0));
    PH(NOPS,                         NOPS, NOPS, 0, MF16(afO, bf1, 4));

    // ---- epilogue: per-row top-2 of u = sb*dot - ca*tb (argtop2 == top2 of inner; sa>0) ----
    int colb = colbase + wc * 64 + l15;
    float sbv[4], tbv[4];
    #pragma unroll
    for (int nf = 0; nf < 4; ++nf) { sbv[nf] = fws[S_L + colb + nf * 16]; tbv[nf] = fws[T_L + colb + nf * 16]; }

    float m1[32], m2[32];
    #pragma unroll
    for (int mf = 0; mf < 8; ++mf) {
        int rw = rowbase + wr * 128 + mf * 16 + rgrp * 4;
        #pragma unroll
        for (int j = 0; j < 4; ++j) {
            float ca = fws[CA_T + rw + j];
            int tgj = tgt[rw + j];
            float a = -3.4e38f, b = -3.4e38f;
            #pragma unroll
            for (int nf = 0; nf < 4; ++nf) {
                float u = sbv[nf] * acc[mf][nf][j] - ca * tbv[nf];
                if (colb + nf * 16 == tgj) u = -3.4e38f;
                float n1 = fmaxf(a, u);
                b = fmaxf(b, fminf(a, u));
                a = n1;
            }
            m1[mf * 4 + j] = a; m2[mf * 4 + j] = b;
        }
    }
    #pragma unroll
    for (int mask = 1; mask <= 8; mask <<= 1)
        #pragma unroll
        for (int i = 0; i < 32; ++i) {
            float o1 = __shfl_xor(m1[i], mask);
            float o2 = __shfl_xor(m2[i], mask);
            float n1 = fmaxf(m1[i], o1);
            m2[i] = fmaxf(fminf(m1[i], o1), fmaxf(m2[i], o2));
            m1[i] = n1;
        }
    if (l15 == 0) {
        #pragma unroll
        for (int mf = 0; mf < 8; ++mf)
            #pragma unroll
            for (int j = 0; j < 4; ++j) {
                int rl = wr * 128 + mf * 16 + rgrp * 4 + j;
                red[rl][wc][0] = m1[mf * 4 + j];
                red[rl][wc][1] = m2[mf * 4 + j];
            }
    }
    __syncthreads();
    if (tid < 256) {
        float p1 = -3.4e38f, p2 = -3.4e38f;
        #pragma unroll
        for (int g = 0; g < 4; ++g) {
            float a1 = red[tid][g][0], a2 = red[tid][g][1];
            float n1 = fmaxf(p1, a1);
            p2 = fmaxf(fminf(p1, a1), fmaxf(p2, a2));
            p1 = n1;
        }
        int row = rowbase + tid;
        fws[PART + ((size_t)row * NCOLT + coltile) * 2 + 0] = p1;
        fws[PART + ((size_t)row * NCOLT + coltile) * 2 + 1] = p2;
    }
}

// ---------------- final: merge partials, arccosh on winners, loss ----------------
__global__ void final_kernel(const char* __restrict__ wsb, const float* __restrict__ curv_log,
                             float* __restrict__ out) {
    const float* fws = (const float*)(wsb + FW_OFF);
    int row = blockIdx.x * 256 + threadIdx.x;
    if (row >= MM) return;
    float curv = __expf(curv_log[0]);
    float rsc = rsqrtf(curv);
    const float* p = fws + PART + (size_t)row * (NCOLT * 2);
    float p1 = -3.4e38f, p2 = -3.4e38f;
    #pragma unroll
    for (int s = 0; s < NCOLT; ++s) {
        float a1 = p[s * 2], a2 = p[s * 2 + 1];
        float n1 = fmaxf(p1, a1);
        p2 = fmaxf(fminf(p1, a1), fmaxf(p2, a2));
        p1 = n1;
    }
    float sa = fws[S_T + row];
    float i1 = sa * p1, i2 = sa * p2;          // back to Lorentz inner
    float cd1 = fmaxf(-curv * i1, 1.0f + EPSF);
    float d1 = __logf(cd1 + sqrtf(cd1 * cd1 - 1.0f)) * rsc;
    float cd2 = fmaxf(-curv * i2, 1.0f + EPSF);
    float d2 = __logf(cd2 + sqrtf(cd2 * cd2 - 1.0f)) * rsc;
    float dp = fws[POS + row];
    float denom = __expf(-dp) + __expf(-d1) + __expf(-d2);
    out[row] = __logf(denom) + dp;
}

extern "C" void kernel_launch(void* const* d_in, const int* in_sizes, int n_in,
                              void* d_out, int out_size, void* d_ws, size_t ws_size,
                              hipStream_t stream) {
    const float* X = (const float*)d_in[0];
    const float* Y = (const float*)d_in[1];
    const int* tgt = (const int*)d_in[2];
    const float* curv_log = (const float*)d_in[3];
    const float* ta_log = (const float*)d_in[4];
    const float* la_log = (const float*)d_in[5];
    char* wsb = (char*)d_ws;
    float* out = (float*)d_out;

    prep_conv_kernel<<<(MM + CC) / 4, 256, 0, stream>>>(X, Y, curv_log, ta_log, la_log, wsb);
    pos_kernel<<<MM / 4, 256, 0, stream>>>(X, Y, tgt, curv_log, wsb);
    main_kernel<<<NROWT * NCOLT, TPB, 0, stream>>>(tgt, wsb);
    final_kernel<<<MM / 256, 256, 0, stream>>>(wsb, curv_log, out);
}